// Round 1
// baseline (10.568 us; speedup 1.0000x reference)
//
#include <hip/hip_runtime.h>

// EmbeddingOnehot: out[n, :] = weights[idx[n], :]
// idx: int32 [16384], weights: f32 [32000, 128], out: f32 [16384, 128]
// one_hot @ W is a pure row gather — no matmul.

#define N_TOKENS 16384
#define VEC 128            // floats per row
#define QUADS_PER_ROW (VEC / 4)   // 32 float4 per row

__global__ __launch_bounds__(256) void embedding_gather_kernel(
    const int* __restrict__ idx,
    const float4* __restrict__ w4,   // weights as float4, 32 per row
    float4* __restrict__ out4)       // output as float4, 32 per row
{
    int i = blockIdx.x * blockDim.x + threadIdx.x;   // 0 .. 16384*32-1
    int token = i >> 5;          // i / 32
    int quad  = i & 31;          // i % 32
    int row = idx[token];        // broadcast within each 32-thread group
    out4[i] = w4[row * QUADS_PER_ROW + quad];
}

extern "C" void kernel_launch(void* const* d_in, const int* in_sizes, int n_in,
                              void* d_out, int out_size, void* d_ws, size_t ws_size,
                              hipStream_t stream) {
    const int*    idx = (const int*)d_in[0];
    const float4* w4  = (const float4*)d_in[1];
    float4*       o4  = (float4*)d_out;

    const int total_quads = N_TOKENS * QUADS_PER_ROW;   // 524288
    const int block = 256;
    const int grid = total_quads / block;               // 2048
    embedding_gather_kernel<<<grid, block, 0, stream>>>(idx, w4, o4);
}

// Round 3
// 9.826 us; speedup vs baseline: 1.0755x; 1.0755x over previous
//
#include <hip/hip_runtime.h>

// EmbeddingOnehot: out[n, :] = weights[idx[n], :]  (one_hot @ W == row gather)
// idx: int32 [16384], weights: f32 [32000, 128], out: f32 [16384, 128]
//
// R2: same as R1 (4 independent gather chains/thread, 512 blocks, nontemporal
// stores) but with clang native vector type so __builtin_nontemporal_store
// compiles (HIP_vector_type float4 is a class, not a native vector).

#define N_TOKENS 16384
#define QUADS_PER_ROW 32                       // 128 floats = 32 x 16B
#define TOTAL_QUADS (N_TOKENS * QUADS_PER_ROW) // 524288
#define NTHREADS (TOTAL_QUADS / 4)             // 131072: 4 quads per thread
#define CHUNK (NTHREADS)

typedef float fvec4 __attribute__((ext_vector_type(4)));

__global__ __launch_bounds__(256) void embedding_gather4_kernel(
    const int* __restrict__ idx,
    const fvec4* __restrict__ w4,
    fvec4* __restrict__ out4)
{
    int j = blockIdx.x * blockDim.x + threadIdx.x;  // 0 .. 131071

    int p0 = j;
    int p1 = j + CHUNK;
    int p2 = j + 2 * CHUNK;
    int p3 = j + 3 * CHUNK;

    // 4 independent idx loads (L1-broadcast within each 32-thread group)
    int r0 = idx[p0 >> 5];
    int r1 = idx[p1 >> 5];
    int r2 = idx[p2 >> 5];
    int r3 = idx[p3 >> 5];

    int q0 = p0 & 31, q1 = p1 & 31, q2 = p2 & 31, q3 = p3 & 31;

    // 4 independent row-gather loads in flight per thread
    fvec4 v0 = w4[r0 * QUADS_PER_ROW + q0];
    fvec4 v1 = w4[r1 * QUADS_PER_ROW + q1];
    fvec4 v2 = w4[r2 * QUADS_PER_ROW + q2];
    fvec4 v3 = w4[r3 * QUADS_PER_ROW + q3];

    __builtin_nontemporal_store(v0, &out4[p0]);
    __builtin_nontemporal_store(v1, &out4[p1]);
    __builtin_nontemporal_store(v2, &out4[p2]);
    __builtin_nontemporal_store(v3, &out4[p3]);
}

extern "C" void kernel_launch(void* const* d_in, const int* in_sizes, int n_in,
                              void* d_out, int out_size, void* d_ws, size_t ws_size,
                              hipStream_t stream) {
    const int*   idx = (const int*)d_in[0];
    const fvec4* w4  = (const fvec4*)d_in[1];
    fvec4*       o4  = (fvec4*)d_out;

    const int block = 256;
    const int grid = NTHREADS / block;   // 512
    embedding_gather4_kernel<<<grid, block, 0, stream>>>(idx, w4, o4);
}